// Round 9
// baseline (251.054 us; speedup 1.0000x reference)
//
#include <hip/hip_runtime.h>

#define INV_SQRT_2F 0.70710678118654752440f

typedef float fvec4 __attribute__((ext_vector_type(4)));

// fp32 -> bf16 bits, round-to-nearest-even (inputs are normal floats here).
static __device__ __forceinline__ unsigned short f2bf(float f)
{
    unsigned int u = __float_as_uint(f);
    u += 0x7fffu + ((u >> 16) & 1u);
    return (unsigned short)(u >> 16);
}

// Combine 4 bf16 (uint2) from src/dst streams into 4 fp32.
static __device__ __forceinline__ fvec4 combine4(uint2 a, uint2 b)
{
    fvec4 r;
    r.x = (__uint_as_float(a.x << 16)         + __uint_as_float(b.x << 16))         * INV_SQRT_2F;
    r.y = (__uint_as_float(a.x & 0xffff0000u) + __uint_as_float(b.x & 0xffff0000u)) * INV_SQRT_2F;
    r.z = (__uint_as_float(a.y << 16)         + __uint_as_float(b.y << 16))         * INV_SQRT_2F;
    r.w = (__uint_as_float(a.y & 0xffff0000u) + __uint_as_float(b.y & 0xffff0000u)) * INV_SQRT_2F;
    return r;
}

// ---------------------------------------------------------------------------
// Prep: pack (src,dst) into one uint (nodes < 65536) -> 1 index load/thread.
// ---------------------------------------------------------------------------
__global__ void pack_sd(const int* __restrict__ src,
                        const int* __restrict__ dst,
                        unsigned int* __restrict__ sd, int edges)
{
    int i = blockIdx.x * blockDim.x + threadIdx.x;
    int stride = gridDim.x * blockDim.x;
    for (; i < edges; i += stride)
        sd[i] = ((unsigned int)src[i] << 16) | (unsigned int)dst[i];
}

// ---------------------------------------------------------------------------
// Kernel 1: per-node channel mix.  y[b,n,o,v] = sum_i W[o,i] * x[b,n,i,v]
// One block per (b,node). Threads 0..63 -> W_src rows, 64..127 -> W_dst rows.
// y stored as bf16 in PHASE-SLICED layout: y[p][node][96] where
// p = b*2 + (o>>5). Each phase slice is a contiguous nodes*192 B region
// (1.92 MB at 10k nodes) so one phase's two slices (src+dst, 3.84 MB) fit a
// single XCD's 4 MiB L2 -> the edge pass's random reads become L2-resident.
// ---------------------------------------------------------------------------
__global__ void __launch_bounds__(128)
node_transform(const float* __restrict__ x,
               const float* __restrict__ W_src,
               const float* __restrict__ W_dst,
               unsigned short* __restrict__ y_src,
               unsigned short* __restrict__ y_dst,
               int nodes, int bn_total)
{
    __shared__ float xs[192];
    int bn = blockIdx.x;               // bn = b*nodes + n  (x is [b][n][192])
    if (bn >= bn_total) return;
    int b = bn / nodes;
    int n = bn - b * nodes;

    const float4* xp = (const float4*)(x + (size_t)bn * 192);
    int t = threadIdx.x;
    if (t < 48) ((float4*)xs)[t] = xp[t];   // 192 floats = 48 float4
    __syncthreads();

    int o = t & 63;
    const float*    W = (t < 64) ? W_src : W_dst;
    unsigned short* y = (t < 64) ? y_src : y_dst;

    const float4* Wrow = (const float4*)(W + o * 64);
    float a0 = 0.f, a1 = 0.f, a2 = 0.f;
#pragma unroll
    for (int i4 = 0; i4 < 16; ++i4) {
        float4 w = Wrow[i4];
        int i = i4 * 4;
        a0 = fmaf(w.x, xs[(i + 0) * 3 + 0], a0);
        a1 = fmaf(w.x, xs[(i + 0) * 3 + 1], a1);
        a2 = fmaf(w.x, xs[(i + 0) * 3 + 2], a2);
        a0 = fmaf(w.y, xs[(i + 1) * 3 + 0], a0);
        a1 = fmaf(w.y, xs[(i + 1) * 3 + 1], a1);
        a2 = fmaf(w.y, xs[(i + 1) * 3 + 2], a2);
        a0 = fmaf(w.z, xs[(i + 2) * 3 + 0], a0);
        a1 = fmaf(w.z, xs[(i + 2) * 3 + 1], a1);
        a2 = fmaf(w.z, xs[(i + 2) * 3 + 2], a2);
        a0 = fmaf(w.w, xs[(i + 3) * 3 + 0], a0);
        a1 = fmaf(w.w, xs[(i + 3) * 3 + 1], a1);
        a2 = fmaf(w.w, xs[(i + 3) * 3 + 2], a2);
    }
    int h = o >> 5;                    // channel half
    int c = o & 31;                    // channel within half
    unsigned short* yp = y + (((size_t)(b * 2 + h) * nodes + n) * 96) + c * 3;
    yp[0] = f2bf(a0);
    yp[1] = f2bf(a1);
    yp[2] = f2bf(a2);
}

// ---------------------------------------------------------------------------
// Kernel 2: PHASED edge gather + combine.  Item index t is phase-major:
// t = (p*edges + e)*24 + j, p = b*2+h in [0,4), j in [0,24).
// Per item: one uint2 (4 bf16) from y_src slice p row src[e], one from y_dst
// slice p row dst[e], combine -> one contiguous fvec4 NT store (R5 lesson:
// lane j <-> out quad j keeps every store instruction lane-contiguous).
// Phase-major order + grid-stride sweep time-localizes each 3.84 MB read
// slice -> XCD-L2 resident.  NT index loads / NT stores avoid evicting y.
// ---------------------------------------------------------------------------
__global__ void __launch_bounds__(256)
edge_combine_phased(const unsigned short* __restrict__ y_src,
                    const unsigned short* __restrict__ y_dst,
                    const unsigned int* __restrict__ sd,
                    float* __restrict__ out,
                    int edges, int nodes)
{
    const int total  = edges * 96;               // 4 phases * 24 quads
    const int stride = gridDim.x * blockDim.x;
    const uint2* ys = (const uint2*)y_src;       // slice row = 24 uint2 (192 B)
    const uint2* yd = (const uint2*)y_dst;
    fvec4*       o4 = (fvec4*)out;

    for (int t = blockIdx.x * blockDim.x + threadIdx.x; t < total; t += stride) {
        int pe = t / 24;                         // p*edges + e   (< 4*edges)
        int j  = t - pe * 24;
        int p  = pe / edges;                     // 0..3 = b*2 + h
        int e  = pe - p * edges;

        unsigned int q = __builtin_nontemporal_load(&sd[e]);
        unsigned int srow = q >> 16;
        unsigned int drow = q & 0xffffu;

        uint2 a = ys[((size_t)p * nodes + srow) * 24 + j];
        uint2 b = yd[((size_t)p * nodes + drow) * 24 + j];

        int bb = p >> 1;
        int h  = p & 1;
        // out fvec4 offset: row = 48 fvec4; h half = 24; quad j
        size_t ob = ((size_t)bb * edges + e) * 48 + h * 24 + j;
        __builtin_nontemporal_store(combine4(a, b), &o4[ob]);
    }
}

// ---------------------------------------------------------------------------
// Phased variant with unpacked indices (nodes >= 65536).
// ---------------------------------------------------------------------------
__global__ void __launch_bounds__(256)
edge_combine_phased_u(const unsigned short* __restrict__ y_src,
                      const unsigned short* __restrict__ y_dst,
                      const int* __restrict__ src,
                      const int* __restrict__ dst,
                      float* __restrict__ out,
                      int edges, int nodes)
{
    const int total  = edges * 96;
    const int stride = gridDim.x * blockDim.x;
    const uint2* ys = (const uint2*)y_src;
    const uint2* yd = (const uint2*)y_dst;
    fvec4*       o4 = (fvec4*)out;

    for (int t = blockIdx.x * blockDim.x + threadIdx.x; t < total; t += stride) {
        int pe = t / 24;
        int j  = t - pe * 24;
        int p  = pe / edges;
        int e  = pe - p * edges;

        unsigned int srow = (unsigned int)__builtin_nontemporal_load(&src[e]);
        unsigned int drow = (unsigned int)__builtin_nontemporal_load(&dst[e]);

        uint2 a = ys[((size_t)p * nodes + srow) * 24 + j];
        uint2 b = yd[((size_t)p * nodes + drow) * 24 + j];

        int bb = p >> 1;
        int h  = p & 1;
        size_t ob = ((size_t)bb * edges + e) * 48 + h * 24 + j;
        __builtin_nontemporal_store(combine4(a, b), &o4[ob]);
    }
}

// ---------------------------------------------------------------------------
// Fallback (ws too small): fused per-edge matmul, fp32.
// ---------------------------------------------------------------------------
__global__ void __launch_bounds__(64)
edge_fused(const float* __restrict__ x,
           const float* __restrict__ W_src,
           const float* __restrict__ W_dst,
           const int* __restrict__ src,
           const int* __restrict__ dst,
           float* __restrict__ out,
           int edges, int nodes)
{
    __shared__ float xs[192];
    __shared__ float xd[192];
    int be = blockIdx.x;
    int b  = be / edges;
    int e  = be - b * edges;
    int s  = src[e];
    int d  = dst[e];
    const float* xps = x + ((size_t)b * nodes + s) * 192;
    const float* xpd = x + ((size_t)b * nodes + d) * 192;
    int t = threadIdx.x;
#pragma unroll
    for (int k = 0; k < 3; ++k) {
        xs[t + 64 * k] = xps[t + 64 * k];
        xd[t + 64 * k] = xpd[t + 64 * k];
    }
    __syncthreads();
    float a0 = 0.f, a1 = 0.f, a2 = 0.f;
#pragma unroll
    for (int i = 0; i < 64; ++i) {
        float ws = W_src[t * 64 + i];
        float wd = W_dst[t * 64 + i];
        a0 += ws * xs[i * 3 + 0] + wd * xd[i * 3 + 0];
        a1 += ws * xs[i * 3 + 1] + wd * xd[i * 3 + 1];
        a2 += ws * xs[i * 3 + 2] + wd * xd[i * 3 + 2];
    }
    float* op = out + ((size_t)b * edges + e) * 192 + t * 3;
    op[0] = a0 * INV_SQRT_2F;
    op[1] = a1 * INV_SQRT_2F;
    op[2] = a2 * INV_SQRT_2F;
}

extern "C" void kernel_launch(void* const* d_in, const int* in_sizes, int n_in,
                              void* d_out, int out_size, void* d_ws, size_t ws_size,
                              hipStream_t stream)
{
    const float* x     = (const float*)d_in[0];
    const float* W_src = (const float*)d_in[1];
    const float* W_dst = (const float*)d_in[2];
    const int*   src   = (const int*)d_in[3];
    const int*   dst   = (const int*)d_in[4];
    float*       out   = (float*)d_out;

    const int batch = 2;
    const int edges = in_sizes[3];
    const int nodes = in_sizes[0] / (batch * 192);   // 192 = dim_in * 3

    const size_t y_elems = (size_t)batch * nodes * 192;          // per array
    const size_t y_bytes = ((y_elems * 2 + 255) / 256) * 256;    // bf16, aligned
    const size_t sd_bytes = (((size_t)edges * 4 + 255) / 256) * 256;
    const size_t needed_packed = 2 * y_bytes + sd_bytes;
    const size_t needed_plain  = 2 * y_bytes;

    char* wsb = (char*)d_ws;
    const int bn_total = batch * nodes;

    if (ws_size >= needed_packed && nodes <= 65535) {
        unsigned short* y_src = (unsigned short*)wsb;
        unsigned short* y_dst = (unsigned short*)(wsb + y_bytes);
        unsigned int*   sd    = (unsigned int*)(wsb + 2 * y_bytes);

        node_transform<<<bn_total, 128, 0, stream>>>(x, W_src, W_dst,
                                                     y_src, y_dst, nodes, bn_total);
        int egrid = (edges + 255) / 256; if (egrid > 1024) egrid = 1024;
        pack_sd<<<egrid, 256, 0, stream>>>(src, dst, sd, edges);
        edge_combine_phased<<<2048, 256, 0, stream>>>(y_src, y_dst, sd, out,
                                                      edges, nodes);
    } else if (ws_size >= needed_plain) {
        unsigned short* y_src = (unsigned short*)wsb;
        unsigned short* y_dst = (unsigned short*)(wsb + y_bytes);
        node_transform<<<bn_total, 128, 0, stream>>>(x, W_src, W_dst,
                                                     y_src, y_dst, nodes, bn_total);
        edge_combine_phased_u<<<2048, 256, 0, stream>>>(y_src, y_dst, src, dst,
                                                        out, edges, nodes);
    } else {
        edge_fused<<<batch * edges, 64, 0, stream>>>(x, W_src, W_dst,
                                                     src, dst, out, edges, nodes);
    }
}

// Round 10
// 249.763 us; speedup vs baseline: 1.0052x; 1.0052x over previous
//
#include <hip/hip_runtime.h>

#define INV_SQRT_2F 0.70710678118654752440f

typedef float fvec4 __attribute__((ext_vector_type(4)));

// fp32 -> bf16 bits, round-to-nearest-even (inputs are normal floats here).
static __device__ __forceinline__ unsigned short f2bf(float f)
{
    unsigned int u = __float_as_uint(f);
    u += 0x7fffu + ((u >> 16) & 1u);
    return (unsigned short)(u >> 16);
}

// Combine 4 bf16 (uint2) from src/dst streams into 4 fp32.
static __device__ __forceinline__ fvec4 combine4(uint2 a, uint2 b)
{
    fvec4 r;
    r.x = (__uint_as_float(a.x << 16)         + __uint_as_float(b.x << 16))         * INV_SQRT_2F;
    r.y = (__uint_as_float(a.x & 0xffff0000u) + __uint_as_float(b.x & 0xffff0000u)) * INV_SQRT_2F;
    r.z = (__uint_as_float(a.y << 16)         + __uint_as_float(b.y << 16))         * INV_SQRT_2F;
    r.w = (__uint_as_float(a.y & 0xffff0000u) + __uint_as_float(b.y & 0xffff0000u)) * INV_SQRT_2F;
    return r;
}

// ---------------------------------------------------------------------------
// Prep: pack (src,dst) into one uint (nodes < 65536) -> 1 index load/thread.
// ---------------------------------------------------------------------------
__global__ void pack_sd(const int* __restrict__ src,
                        const int* __restrict__ dst,
                        unsigned int* __restrict__ sd, int edges)
{
    int i = blockIdx.x * blockDim.x + threadIdx.x;
    int stride = gridDim.x * blockDim.x;
    for (; i < edges; i += stride)
        sd[i] = ((unsigned int)src[i] << 16) | (unsigned int)dst[i];
}

// ---------------------------------------------------------------------------
// Kernel 1: per-node channel mix.  y[b,n,o,v] = sum_i W[o,i] * x[b,n,i,v]
// One block per (b,node). Threads 0..63 -> W_src rows, 64..127 -> W_dst rows.
// y stored as bf16 in PHASE-SLICED layout: y[p][node][96] where
// p = b*2 + (o>>5). Each phase slice is contiguous nodes*192 B (1.92 MB at
// 10k nodes); one phase's two slices (src+dst, 3.84 MB) fit one XCD's 4 MiB
// L2 -> the edge pass's random reads become L2-resident when phases are
// pinned to XCDs.
// ---------------------------------------------------------------------------
__global__ void __launch_bounds__(128)
node_transform(const float* __restrict__ x,
               const float* __restrict__ W_src,
               const float* __restrict__ W_dst,
               unsigned short* __restrict__ y_src,
               unsigned short* __restrict__ y_dst,
               int nodes, int bn_total)
{
    __shared__ float xs[192];
    int bn = blockIdx.x;               // bn = b*nodes + n  (x is [b][n][192])
    if (bn >= bn_total) return;
    int b = bn / nodes;
    int n = bn - b * nodes;

    const float4* xp = (const float4*)(x + (size_t)bn * 192);
    int t = threadIdx.x;
    if (t < 48) ((float4*)xs)[t] = xp[t];   // 192 floats = 48 float4
    __syncthreads();

    int o = t & 63;
    const float*    W = (t < 64) ? W_src : W_dst;
    unsigned short* y = (t < 64) ? y_src : y_dst;

    const float4* Wrow = (const float4*)(W + o * 64);
    float a0 = 0.f, a1 = 0.f, a2 = 0.f;
#pragma unroll
    for (int i4 = 0; i4 < 16; ++i4) {
        float4 w = Wrow[i4];
        int i = i4 * 4;
        a0 = fmaf(w.x, xs[(i + 0) * 3 + 0], a0);
        a1 = fmaf(w.x, xs[(i + 0) * 3 + 1], a1);
        a2 = fmaf(w.x, xs[(i + 0) * 3 + 2], a2);
        a0 = fmaf(w.y, xs[(i + 1) * 3 + 0], a0);
        a1 = fmaf(w.y, xs[(i + 1) * 3 + 1], a1);
        a2 = fmaf(w.y, xs[(i + 1) * 3 + 2], a2);
        a0 = fmaf(w.z, xs[(i + 2) * 3 + 0], a0);
        a1 = fmaf(w.z, xs[(i + 2) * 3 + 1], a1);
        a2 = fmaf(w.z, xs[(i + 2) * 3 + 2], a2);
        a0 = fmaf(w.w, xs[(i + 3) * 3 + 0], a0);
        a1 = fmaf(w.w, xs[(i + 3) * 3 + 1], a1);
        a2 = fmaf(w.w, xs[(i + 3) * 3 + 2], a2);
    }
    int h = o >> 5;                    // channel half
    int c = o & 31;                    // channel within half
    unsigned short* yp = y + (((size_t)(b * 2 + h) * nodes + n) * 96) + c * 3;
    yp[0] = f2bf(a0);
    yp[1] = f2bf(a1);
    yp[2] = f2bf(a2);
}

// ---------------------------------------------------------------------------
// Kernel 2: XCD-PINNED phased edge combine.  Blocks land on XCDs round-robin
// (xcd = blockIdx.x & 7, measured m09); phase p = xcd & 3 is served by XCDs
// {p, p+4}, each keeping phase p's 3.84 MB read slice resident in its own
// 4 MiB L2.  Within a phase: 512 blocks sweep edges*24 quad-items.
// Correctness does NOT depend on the XCD mapping (any block may process any
// item of its phase); only locality does.  Stores: one fvec4 per item,
// contiguous in j (384 B per half-row chunk, full cache lines), NT.
// ---------------------------------------------------------------------------
__global__ void __launch_bounds__(256)
edge_combine_xcd(const unsigned short* __restrict__ y_src,
                 const unsigned short* __restrict__ y_dst,
                 const unsigned int* __restrict__ sd,
                 float* __restrict__ out,
                 int edges, int nodes)
{
    const uint2* ys = (const uint2*)y_src;       // slice row = 24 uint2 (192 B)
    const uint2* yd = (const uint2*)y_dst;
    fvec4*       o4 = (fvec4*)out;

    int bid  = blockIdx.x;
    int xcd  = bid & 7;                          // round-robin XCD id
    int p    = xcd & 3;                          // phase 0..3 = b*2 + h
    int rep  = bid >> 3;                         // replica within this xcd
    int half = xcd >> 2;                         // which of the 2 XCDs on p
    int nrep = (int)(gridDim.x >> 3);            // blocks per xcd
    int tid  = ((rep * 2 + half) * (int)blockDim.x) + (int)threadIdx.x;
    int nthr = nrep * 2 * (int)blockDim.x;       // threads serving phase p

    const uint2* ysp = ys + (size_t)p * nodes * 24;
    const uint2* ydp = yd + (size_t)p * nodes * 24;
    const int bb = p >> 1;
    const int h  = p & 1;
    const int total = edges * 24;

    for (int t = tid; t < total; t += nthr) {
        int e = t / 24;
        int j = t - e * 24;

        unsigned int q = __builtin_nontemporal_load(&sd[e]);
        uint2 a = ysp[(size_t)(q >> 16)     * 24 + j];
        uint2 b = ydp[(size_t)(q & 0xffffu) * 24 + j];

        size_t ob = ((size_t)bb * edges + e) * 48 + h * 24 + j;
        __builtin_nontemporal_store(combine4(a, b), &o4[ob]);
    }
}

// ---------------------------------------------------------------------------
// Phased variant with unpacked indices (nodes >= 65536), no XCD pinning.
// ---------------------------------------------------------------------------
__global__ void __launch_bounds__(256)
edge_combine_phased_u(const unsigned short* __restrict__ y_src,
                      const unsigned short* __restrict__ y_dst,
                      const int* __restrict__ src,
                      const int* __restrict__ dst,
                      float* __restrict__ out,
                      int edges, int nodes)
{
    const int total  = edges * 96;
    const int stride = gridDim.x * blockDim.x;
    const uint2* ys = (const uint2*)y_src;
    const uint2* yd = (const uint2*)y_dst;
    fvec4*       o4 = (fvec4*)out;

    for (int t = blockIdx.x * blockDim.x + threadIdx.x; t < total; t += stride) {
        int pe = t / 24;
        int j  = t - pe * 24;
        int p  = pe / edges;
        int e  = pe - p * edges;

        unsigned int srow = (unsigned int)__builtin_nontemporal_load(&src[e]);
        unsigned int drow = (unsigned int)__builtin_nontemporal_load(&dst[e]);

        uint2 a = ys[((size_t)p * nodes + srow) * 24 + j];
        uint2 b = yd[((size_t)p * nodes + drow) * 24 + j];

        int bb = p >> 1;
        int h  = p & 1;
        size_t ob = ((size_t)bb * edges + e) * 48 + h * 24 + j;
        __builtin_nontemporal_store(combine4(a, b), &o4[ob]);
    }
}

// ---------------------------------------------------------------------------
// Fallback (ws too small): fused per-edge matmul, fp32.
// ---------------------------------------------------------------------------
__global__ void __launch_bounds__(64)
edge_fused(const float* __restrict__ x,
           const float* __restrict__ W_src,
           const float* __restrict__ W_dst,
           const int* __restrict__ src,
           const int* __restrict__ dst,
           float* __restrict__ out,
           int edges, int nodes)
{
    __shared__ float xs[192];
    __shared__ float xd[192];
    int be = blockIdx.x;
    int b  = be / edges;
    int e  = be - b * edges;
    int s  = src[e];
    int d  = dst[e];
    const float* xps = x + ((size_t)b * nodes + s) * 192;
    const float* xpd = x + ((size_t)b * nodes + d) * 192;
    int t = threadIdx.x;
#pragma unroll
    for (int k = 0; k < 3; ++k) {
        xs[t + 64 * k] = xps[t + 64 * k];
        xd[t + 64 * k] = xpd[t + 64 * k];
    }
    __syncthreads();
    float a0 = 0.f, a1 = 0.f, a2 = 0.f;
#pragma unroll
    for (int i = 0; i < 64; ++i) {
        float ws = W_src[t * 64 + i];
        float wd = W_dst[t * 64 + i];
        a0 += ws * xs[i * 3 + 0] + wd * xd[i * 3 + 0];
        a1 += ws * xs[i * 3 + 1] + wd * xd[i * 3 + 1];
        a2 += ws * xs[i * 3 + 2] + wd * xd[i * 3 + 2];
    }
    float* op = out + ((size_t)b * edges + e) * 192 + t * 3;
    op[0] = a0 * INV_SQRT_2F;
    op[1] = a1 * INV_SQRT_2F;
    op[2] = a2 * INV_SQRT_2F;
}

extern "C" void kernel_launch(void* const* d_in, const int* in_sizes, int n_in,
                              void* d_out, int out_size, void* d_ws, size_t ws_size,
                              hipStream_t stream)
{
    const float* x     = (const float*)d_in[0];
    const float* W_src = (const float*)d_in[1];
    const float* W_dst = (const float*)d_in[2];
    const int*   src   = (const int*)d_in[3];
    const int*   dst   = (const int*)d_in[4];
    float*       out   = (float*)d_out;

    const int batch = 2;
    const int edges = in_sizes[3];
    const int nodes = in_sizes[0] / (batch * 192);   // 192 = dim_in * 3

    const size_t y_elems = (size_t)batch * nodes * 192;          // per array
    const size_t y_bytes = ((y_elems * 2 + 255) / 256) * 256;    // bf16, aligned
    const size_t sd_bytes = (((size_t)edges * 4 + 255) / 256) * 256;
    const size_t needed_packed = 2 * y_bytes + sd_bytes;
    const size_t needed_plain  = 2 * y_bytes;

    char* wsb = (char*)d_ws;
    const int bn_total = batch * nodes;

    if (ws_size >= needed_packed && nodes <= 65535) {
        unsigned short* y_src = (unsigned short*)wsb;
        unsigned short* y_dst = (unsigned short*)(wsb + y_bytes);
        unsigned int*   sd    = (unsigned int*)(wsb + 2 * y_bytes);

        node_transform<<<bn_total, 128, 0, stream>>>(x, W_src, W_dst,
                                                     y_src, y_dst, nodes, bn_total);
        int egrid = (edges + 255) / 256; if (egrid > 1024) egrid = 1024;
        pack_sd<<<egrid, 256, 0, stream>>>(src, dst, sd, edges);
        // grid must be a multiple of 8 for the XCD round-robin partition
        edge_combine_xcd<<<2048, 256, 0, stream>>>(y_src, y_dst, sd, out,
                                                   edges, nodes);
    } else if (ws_size >= needed_plain) {
        unsigned short* y_src = (unsigned short*)wsb;
        unsigned short* y_dst = (unsigned short*)(wsb + y_bytes);
        node_transform<<<bn_total, 128, 0, stream>>>(x, W_src, W_dst,
                                                     y_src, y_dst, nodes, bn_total);
        edge_combine_phased_u<<<2048, 256, 0, stream>>>(y_src, y_dst, src, dst,
                                                        out, edges, nodes);
    } else {
        edge_fused<<<batch * edges, 64, 0, stream>>>(x, W_src, W_dst,
                                                     src, dst, out, edges, nodes);
    }
}

// Round 11
// 210.357 us; speedup vs baseline: 1.1935x; 1.1873x over previous
//
#include <hip/hip_runtime.h>

#define INV_SQRT_2F 0.70710678118654752440f

typedef float fvec4 __attribute__((ext_vector_type(4)));

// fp32 -> bf16 bits, round-to-nearest-even (inputs are normal floats here).
static __device__ __forceinline__ unsigned short f2bf(float f)
{
    unsigned int u = __float_as_uint(f);
    u += 0x7fffu + ((u >> 16) & 1u);
    return (unsigned short)(u >> 16);
}

// Combine 4 bf16 (uint2) from src/dst streams into 4 fp32.
static __device__ __forceinline__ fvec4 combine4(uint2 a, uint2 b)
{
    fvec4 r;
    r.x = (__uint_as_float(a.x << 16)         + __uint_as_float(b.x << 16))         * INV_SQRT_2F;
    r.y = (__uint_as_float(a.x & 0xffff0000u) + __uint_as_float(b.x & 0xffff0000u)) * INV_SQRT_2F;
    r.z = (__uint_as_float(a.y << 16)         + __uint_as_float(b.y << 16))         * INV_SQRT_2F;
    r.w = (__uint_as_float(a.y & 0xffff0000u) + __uint_as_float(b.y & 0xffff0000u)) * INV_SQRT_2F;
    return r;
}

// 8-byte lane exchange with lane^1.
static __device__ __forceinline__ uint2 xchg1(uint2 v)
{
    uint2 r;
    r.x = __shfl_xor((unsigned int)v.x, 1);
    r.y = __shfl_xor((unsigned int)v.y, 1);
    return r;
}

// ---------------------------------------------------------------------------
// Prep: pack (src,dst) into one uint (nodes < 65536) -> 1 index load/thread.
// ---------------------------------------------------------------------------
__global__ void pack_sd(const int* __restrict__ src,
                        const int* __restrict__ dst,
                        unsigned int* __restrict__ sd, int edges)
{
    int i = blockIdx.x * blockDim.x + threadIdx.x;
    int stride = gridDim.x * blockDim.x;
    for (; i < edges; i += stride)
        sd[i] = ((unsigned int)src[i] << 16) | (unsigned int)dst[i];
}

// ---------------------------------------------------------------------------
// Kernel 1: per-node channel mix.  y[b,n,o,v] = sum_i W[o,i] * x[b,n,i,v]
// One block per (b,node). Threads 0..63 -> W_src rows, 64..127 -> W_dst rows.
// y stored as bf16, batch-interleaved per node (768 B contiguous per node).
// ---------------------------------------------------------------------------
__global__ void __launch_bounds__(128)
node_transform(const float* __restrict__ x,
               const float* __restrict__ W_src,
               const float* __restrict__ W_dst,
               unsigned short* __restrict__ y_src,
               unsigned short* __restrict__ y_dst,
               int nodes, int bn_total)
{
    __shared__ float xs[192];
    int bn = blockIdx.x;               // bn = b*nodes + n  (x is [b][n][192])
    if (bn >= bn_total) return;
    int b = bn / nodes;
    int n = bn - b * nodes;

    const float4* xp = (const float4*)(x + (size_t)bn * 192);
    int t = threadIdx.x;
    if (t < 48) ((float4*)xs)[t] = xp[t];   // 192 floats = 48 float4
    __syncthreads();

    int o = t & 63;
    const float*    W = (t < 64) ? W_src : W_dst;
    unsigned short* y = (t < 64) ? y_src : y_dst;

    const float4* Wrow = (const float4*)(W + o * 64);
    float a0 = 0.f, a1 = 0.f, a2 = 0.f;
#pragma unroll
    for (int i4 = 0; i4 < 16; ++i4) {
        float4 w = Wrow[i4];
        int i = i4 * 4;
        a0 = fmaf(w.x, xs[(i + 0) * 3 + 0], a0);
        a1 = fmaf(w.x, xs[(i + 0) * 3 + 1], a1);
        a2 = fmaf(w.x, xs[(i + 0) * 3 + 2], a2);
        a0 = fmaf(w.y, xs[(i + 1) * 3 + 0], a0);
        a1 = fmaf(w.y, xs[(i + 1) * 3 + 1], a1);
        a2 = fmaf(w.y, xs[(i + 1) * 3 + 2], a2);
        a0 = fmaf(w.z, xs[(i + 2) * 3 + 0], a0);
        a1 = fmaf(w.z, xs[(i + 2) * 3 + 1], a1);
        a2 = fmaf(w.z, xs[(i + 2) * 3 + 2], a2);
        a0 = fmaf(w.w, xs[(i + 3) * 3 + 0], a0);
        a1 = fmaf(w.w, xs[(i + 3) * 3 + 1], a1);
        a2 = fmaf(w.w, xs[(i + 3) * 3 + 2], a2);
    }
    unsigned short* yp = y + ((size_t)n * 2 + b) * 192 + o * 3;
    yp[0] = f2bf(a0);
    yp[1] = f2bf(a1);
    yp[2] = f2bf(a2);
}

// ---------------------------------------------------------------------------
// Kernel 2: paired-gather edge combine.  Item = (g, j): 4 edges
// {2g, 2g+1, 2Q+2g, 2Q+2g+1} at out-quad j.  Lane pairs (j even, j+1) share
// an edge: even lane loads 16 B of the SRC row, odd lane 16 B of the DST row
// (both batches), one 8 B shfl_xor exchange delivers both quads to both lanes.
// Stores stay per-instruction lane-contiguous (R5 lesson), NT (R3 lesson).
// Node row in uint4 units: 48 per node (24 per batch).
// ---------------------------------------------------------------------------
__global__ void __launch_bounds__(256)
edge_combine_p(const unsigned short* __restrict__ y_src,
               const unsigned short* __restrict__ y_dst,
               const unsigned int* __restrict__ sd,
               float* __restrict__ out,
               int edges)
{
    const int Q = edges >> 2;                // quads of edges; tail handled separately
    const int total = Q * 48;                // even (48 even) -> pair-safe guard
    const int stride = gridDim.x * blockDim.x;
    const uint4* ys4 = (const uint4*)y_src;
    const uint4* yd4 = (const uint4*)y_dst;
    fvec4*       o4  = (fvec4*)out;

    for (int t = blockIdx.x * blockDim.x + threadIdx.x; t < total; t += stride) {
        int g  = t / 48;
        int j  = t - g * 48;                 // parity(j) == parity(lane)
        int par = j & 1;
        int jj  = j >> 1;                    // uint4 index within batch-0 half of row

        uint2 p01 = *(const uint2*)&sd[2 * g];           // edges 2g, 2g+1
        uint2 p23 = *(const uint2*)&sd[2 * Q + 2 * g];   // edges 2Q+2g, 2Q+2g+1
        unsigned int pk[4] = { p01.x, p01.y, p23.x, p23.y };
        int ek[4] = { 2 * g, 2 * g + 1, 2 * Q + 2 * g, 2 * Q + 2 * g + 1 };

        const uint4* base = par ? yd4 : ys4;

#pragma unroll
        for (int k = 0; k < 4; ++k) {
            unsigned int row = par ? (pk[k] & 0xffffu) : (pk[k] >> 16);
            const uint4* rp = base + (size_t)row * 48 + jj;
            uint4 v0 = rp[0];                // batch 0: quads {J, J+1}
            uint4 v1 = rp[24];               // batch 1

            // batch 0: keep own quad, exchange the other with lane^1
            uint2 kept0 = par ? make_uint2(v0.z, v0.w) : make_uint2(v0.x, v0.y);
            uint2 send0 = par ? make_uint2(v0.x, v0.y) : make_uint2(v0.z, v0.w);
            uint2 recv0 = xchg1(send0);
            __builtin_nontemporal_store(combine4(kept0, recv0),
                                        &o4[(size_t)ek[k] * 48 + j]);

            // batch 1
            uint2 kept1 = par ? make_uint2(v1.z, v1.w) : make_uint2(v1.x, v1.y);
            uint2 send1 = par ? make_uint2(v1.x, v1.y) : make_uint2(v1.z, v1.w);
            uint2 recv1 = xchg1(send1);
            __builtin_nontemporal_store(combine4(kept1, recv1),
                                        &o4[((size_t)edges + ek[k]) * 48 + j]);
        }
    }
}

// Tail kernel: edges in [e_begin, edges), scalar per-quad (R4-style).
__global__ void edge_combine_tail(const unsigned short* __restrict__ y_src,
                                  const unsigned short* __restrict__ y_dst,
                                  const unsigned int* __restrict__ sd,
                                  float* __restrict__ out,
                                  int edges, int e_begin)
{
    int idx = blockIdx.x * blockDim.x + threadIdx.x;
    int nt = (edges - e_begin) * 48;
    if (idx >= nt) return;
    int e = e_begin + idx / 48;
    int j = idx - (idx / 48) * 48;
    const uint2* ys = (const uint2*)y_src;
    const uint2* yd = (const uint2*)y_dst;
    fvec4*       o4 = (fvec4*)out;
    unsigned int p = sd[e];
    size_t s = (size_t)(p >> 16)     * 96 + j;
    size_t d = (size_t)(p & 0xffffu) * 96 + j;
    uint2 a0 = ys[s];
    uint2 b0 = yd[d];
    uint2 a1 = ys[s + 48];
    uint2 b1 = yd[d + 48];
    __builtin_nontemporal_store(combine4(a0, b0), &o4[(size_t)e * 48 + j]);
    __builtin_nontemporal_store(combine4(a1, b1), &o4[((size_t)edges + e) * 48 + j]);
}

// ---------------------------------------------------------------------------
// Unsorted R4 variant (fallback when nodes don't fit 16-bit packing).
// ---------------------------------------------------------------------------
__global__ void __launch_bounds__(256)
edge_combine(const unsigned short* __restrict__ y_src,
             const unsigned short* __restrict__ y_dst,
             const int* __restrict__ src,
             const int* __restrict__ dst,
             float* __restrict__ out,
             int edges)
{
    const int total  = edges * 48;
    const int stride = gridDim.x * blockDim.x;
    const uint2* ys = (const uint2*)y_src;
    const uint2* yd = (const uint2*)y_dst;
    fvec4*       o4 = (fvec4*)out;

    for (int t = blockIdx.x * blockDim.x + threadIdx.x; t < total; t += stride) {
        int e = t / 48;
        int j = t - e * 48;
        size_t sb = (size_t)src[e] * 96 + j;
        size_t db = (size_t)dst[e] * 96 + j;

        uint2 a0 = ys[sb];
        uint2 b0 = yd[db];
        uint2 a1 = ys[sb + 48];
        uint2 b1 = yd[db + 48];

        __builtin_nontemporal_store(combine4(a0, b0), &o4[(size_t)e * 48 + j]);
        __builtin_nontemporal_store(combine4(a1, b1), &o4[((size_t)edges + e) * 48 + j]);
    }
}

// ---------------------------------------------------------------------------
// Fallback (ws too small): fused per-edge matmul, fp32.
// ---------------------------------------------------------------------------
__global__ void __launch_bounds__(64)
edge_fused(const float* __restrict__ x,
           const float* __restrict__ W_src,
           const float* __restrict__ W_dst,
           const int* __restrict__ src,
           const int* __restrict__ dst,
           float* __restrict__ out,
           int edges, int nodes)
{
    __shared__ float xs[192];
    __shared__ float xd[192];
    int be = blockIdx.x;
    int b  = be / edges;
    int e  = be - b * edges;
    int s  = src[e];
    int d  = dst[e];
    const float* xps = x + ((size_t)b * nodes + s) * 192;
    const float* xpd = x + ((size_t)b * nodes + d) * 192;
    int t = threadIdx.x;
#pragma unroll
    for (int k = 0; k < 3; ++k) {
        xs[t + 64 * k] = xps[t + 64 * k];
        xd[t + 64 * k] = xpd[t + 64 * k];
    }
    __syncthreads();
    float a0 = 0.f, a1 = 0.f, a2 = 0.f;
#pragma unroll
    for (int i = 0; i < 64; ++i) {
        float ws = W_src[t * 64 + i];
        float wd = W_dst[t * 64 + i];
        a0 += ws * xs[i * 3 + 0] + wd * xd[i * 3 + 0];
        a1 += ws * xs[i * 3 + 1] + wd * xd[i * 3 + 1];
        a2 += ws * xs[i * 3 + 2] + wd * xd[i * 3 + 2];
    }
    float* op = out + ((size_t)b * edges + e) * 192 + t * 3;
    op[0] = a0 * INV_SQRT_2F;
    op[1] = a1 * INV_SQRT_2F;
    op[2] = a2 * INV_SQRT_2F;
}

extern "C" void kernel_launch(void* const* d_in, const int* in_sizes, int n_in,
                              void* d_out, int out_size, void* d_ws, size_t ws_size,
                              hipStream_t stream)
{
    const float* x     = (const float*)d_in[0];
    const float* W_src = (const float*)d_in[1];
    const float* W_dst = (const float*)d_in[2];
    const int*   src   = (const int*)d_in[3];
    const int*   dst   = (const int*)d_in[4];
    float*       out   = (float*)d_out;

    const int batch = 2;
    const int edges = in_sizes[3];
    const int nodes = in_sizes[0] / (batch * 192);   // 192 = dim_in * 3

    const size_t y_elems = (size_t)batch * nodes * 192;          // per array
    const size_t y_bytes = ((y_elems * 2 + 255) / 256) * 256;    // bf16, aligned
    const size_t sd_bytes = (((size_t)edges * 4 + 255) / 256) * 256;
    const size_t needed_packed = 2 * y_bytes + sd_bytes;
    const size_t needed_plain  = 2 * y_bytes;

    char* wsb = (char*)d_ws;
    const int bn_total = batch * nodes;

    if (ws_size >= needed_packed && nodes <= 65535 && edges >= 4) {
        unsigned short* y_src = (unsigned short*)wsb;
        unsigned short* y_dst = (unsigned short*)(wsb + y_bytes);
        unsigned int*   sd    = (unsigned int*)(wsb + 2 * y_bytes);

        node_transform<<<bn_total, 128, 0, stream>>>(x, W_src, W_dst,
                                                     y_src, y_dst, nodes, bn_total);
        int egrid = (edges + 255) / 256; if (egrid > 1024) egrid = 1024;
        pack_sd<<<egrid, 256, 0, stream>>>(src, dst, sd, edges);
        edge_combine_p<<<2048, 256, 0, stream>>>(y_src, y_dst, sd, out, edges);
        int tail = edges & 3;
        if (tail)
            edge_combine_tail<<<1, 256, 0, stream>>>(y_src, y_dst, sd, out,
                                                     edges, edges - tail);
    } else if (ws_size >= needed_plain) {
        unsigned short* y_src = (unsigned short*)wsb;
        unsigned short* y_dst = (unsigned short*)(wsb + y_bytes);
        node_transform<<<bn_total, 128, 0, stream>>>(x, W_src, W_dst,
                                                     y_src, y_dst, nodes, bn_total);
        edge_combine<<<2048, 256, 0, stream>>>(y_src, y_dst, src, dst, out, edges);
    } else {
        edge_fused<<<batch * edges, 64, 0, stream>>>(x, W_src, W_dst,
                                                     src, dst, out, edges, nodes);
    }
}